// Round 1
// baseline (593.670 us; speedup 1.0000x reference)
//
#include <hip/hip_runtime.h>

// ---------------------------------------------------------------------------
// RGAT encoder: N=50000 nodes, E=800000 edges, R=8 relations, IN=H=128, B=10.
// Pipeline per conv layer:
//   si/sj score tables (f32)  +  xW[r] = x @ W[r] (bf16 MFMA GEMM)
//   -> fused online-softmax + weighted gather per target (CSR, one wave/target)
// Final: h2 @ Wl^T + bl (MFMA GEMM, f32 out).
// CSR built once (same graph both layers).
// ---------------------------------------------------------------------------

typedef unsigned int uint;
typedef unsigned short ushort_t;

using bf16x8 = __attribute__((ext_vector_type(8))) __bf16;
using f32x4  = __attribute__((ext_vector_type(4))) float;

__device__ __forceinline__ ushort_t fToBf(float f) {
  uint u = __float_as_uint(f);
  u += 0x7FFFu + ((u >> 16) & 1);   // round-to-nearest-even
  return (ushort_t)(u >> 16);
}
__device__ __forceinline__ float bfToF(ushort_t h) {
  return __uint_as_float(((uint)h) << 16);
}

// ------------------------------- CSR build ---------------------------------

__global__ void k_count(const int* __restrict__ tgt, int* __restrict__ deg, int E) {
  int e = blockIdx.x * 256 + threadIdx.x;
  if (e < E) atomicAdd(&deg[tgt[e]], 1);
}

__global__ void k_scanA(const int* __restrict__ deg, int* __restrict__ incl,
                        int* __restrict__ bsum, int n) {
  __shared__ int s[256];
  int tid = threadIdx.x;
  int i = blockIdx.x * 256 + tid;
  int v = (i < n) ? deg[i] : 0;
  s[tid] = v;
  __syncthreads();
  for (int off = 1; off < 256; off <<= 1) {
    int t = (tid >= off) ? s[tid - off] : 0;
    __syncthreads();
    s[tid] += t;
    __syncthreads();
  }
  if (i < n) incl[i] = s[tid];
  if (tid == 255) bsum[blockIdx.x] = s[255];
}

__global__ void k_scanB(int* __restrict__ bsum, int nb) {
  __shared__ int s[256];
  int tid = threadIdx.x;
  int v = (tid < nb) ? bsum[tid] : 0;
  s[tid] = v;
  __syncthreads();
  for (int off = 1; off < 256; off <<= 1) {
    int t = (tid >= off) ? s[tid - off] : 0;
    __syncthreads();
    s[tid] += t;
    __syncthreads();
  }
  if (tid < nb) bsum[tid] = s[tid] - v;   // exclusive
}

__global__ void k_scanC(const int* __restrict__ deg, const int* __restrict__ incl,
                        const int* __restrict__ bsum, int* __restrict__ rowptr,
                        int n, int E) {
  int i = blockIdx.x * 256 + threadIdx.x;
  if (i < n) {
    rowptr[i] = bsum[blockIdx.x] + incl[i] - deg[i];  // exclusive scan
    if (i == n - 1) rowptr[n] = E;
  }
}

__global__ void k_scatter(const int* __restrict__ src, const int* __restrict__ tgt,
                          const int* __restrict__ et, const int* __restrict__ rowptr,
                          int* __restrict__ cursor, int* __restrict__ sorted, int E) {
  int e = blockIdx.x * 256 + threadIdx.x;
  if (e >= E) return;
  int t = tgt[e];
  int pos = atomicAdd(&cursor[t], 1);
  sorted[rowptr[t] + pos] = src[e] | (et[e] << 16);   // src < 65536, rel < 8
}

// ------------------------------ conversions --------------------------------

__global__ void k_cvt(const float* __restrict__ in, ushort_t* __restrict__ out, int n4) {
  int i = blockIdx.x * 256 + threadIdx.x;
  if (i >= n4) return;
  float4 v = ((const float4*)in)[i];
  ushort4 o;
  o.x = fToBf(v.x); o.y = fToBf(v.y); o.z = fToBf(v.z); o.w = fToBf(v.w);
  ((ushort4*)out)[i] = o;
}

// WT[r][n][k] = W[r][k][n]  (bf16) — fragment-ready layout for MFMA B operand.
__global__ void k_wT(const float* __restrict__ W, ushort_t* __restrict__ WT) {
  int rn = blockIdx.x;          // r*128 + n
  int r = rn >> 7, n = rn & 127;
  int k = threadIdx.x;          // 128 threads
  WT[(size_t)rn * 128 + k] = fToBf(W[((size_t)r * 128 + k) * 128 + n]);
}

// Wq[r][kin] = sum_h W[r][kin][h] * q[h]; same for Wk. 2048 dot products.
__global__ void k_wqwk(const float* __restrict__ W, const float* __restrict__ q,
                       const float* __restrict__ k, float* __restrict__ Wq,
                       float* __restrict__ Wk) {
  int g = blockIdx.x * 256 + threadIdx.x;   // 0..2047
  if (g >= 2048) return;
  int which = g >> 10;
  int idx = g & 1023;                        // r*128 + kin
  const float* w = W + (size_t)idx * 128;
  const float* v = which ? k : q;
  float s = 0.f;
  #pragma unroll 8
  for (int h = 0; h < 128; h++) s += w[h] * v[h];
  (which ? Wk : Wq)[idx] = s;
}

// ------------------------- attention score tables --------------------------
// si[n][r] = feat[n] . Wq[r]  (target/q side), sj[n][r] = feat[n] . Wk[r].
// One wave per node; butterfly reductions.

template <bool BF16IN>
__global__ void k_sisj(const void* __restrict__ feat, const float* __restrict__ Wq,
                       const float* __restrict__ Wk, float* __restrict__ si,
                       float* __restrict__ sj, int n) {
  __shared__ float sq[1024];
  __shared__ float sk[1024];
  int tid = threadIdx.x;
  for (int i = tid; i < 1024; i += 256) { sq[i] = Wq[i]; sk[i] = Wk[i]; }
  __syncthreads();
  int wv = tid >> 6, lane = tid & 63;
  int node = blockIdx.x * 4 + wv;
  if (node >= n) return;
  float x0, x1;
  if (BF16IN) {
    const ushort_t* f = (const ushort_t*)feat + (size_t)node * 128;
    x0 = bfToF(f[lane]); x1 = bfToF(f[lane + 64]);
  } else {
    const float* f = (const float*)feat + (size_t)node * 128;
    x0 = f[lane]; x1 = f[lane + 64];
  }
  #pragma unroll
  for (int r = 0; r < 8; r++) {
    float pq = x0 * sq[r * 128 + lane] + x1 * sq[r * 128 + lane + 64];
    float pk = x0 * sk[r * 128 + lane] + x1 * sk[r * 128 + lane + 64];
    #pragma unroll
    for (int off = 32; off; off >>= 1) {
      pq += __shfl_xor(pq, off, 64);
      pk += __shfl_xor(pk, off, 64);
    }
    if (lane == 0) { si[node * 8 + r] = pq; sj[node * 8 + r] = pk; }
  }
}

// ------------------------------- MFMA GEMM ---------------------------------
// C[m,n] = sum_k A[m,k]*B[k,n], M x 128, K=128. A bf16 row-major [M,128].
// BT bf16 [128(n)][128(k)] (i.e. B transposed, fragment-ready rows).
// Block: 256 thr = 4 waves; tile 64 rows x 128 cols; K=128 staged whole.
// MODE 0: bf16 out to C + blockIdx.y*M*128 (per-relation xW). MODE 1: f32 out + bias.

#define LDA 136   // padded LDS stride (bf16 elems): 272 B, +4 banks/row

template <int MODE>
__global__ void k_gemm(const ushort_t* __restrict__ A, const ushort_t* __restrict__ BT,
                       void* __restrict__ Cout, const float* __restrict__ bias, int M) {
  __shared__ ushort_t As[64 * LDA];
  __shared__ ushort_t Bs[128 * LDA];
  int tid = threadIdx.x;
  int row0 = blockIdx.x * 64;
  const ushort_t* Bt = BT + (size_t)blockIdx.y * 128 * 128;

  // stage A (64x128 bf16), zero-fill OOB rows
  for (int c = tid; c < 1024; c += 256) {
    int r = c >> 4, off = (c & 15) * 8;
    int4 v = {0, 0, 0, 0};
    if (row0 + r < M) v = *(const int4*)(A + (size_t)(row0 + r) * 128 + off);
    *(int4*)(As + r * LDA + off) = v;
  }
  // stage BT (128x128 bf16)
  for (int c = tid; c < 2048; c += 256) {
    int nn = c >> 4, off = (c & 15) * 8;
    *(int4*)(Bs + nn * LDA + off) = *(const int4*)(Bt + (size_t)nn * 128 + off);
  }
  __syncthreads();

  int wv = tid >> 6, lane = tid & 63;
  int l15 = lane & 15, quad = lane >> 4;
  int wr = wv * 16;

  bf16x8 afr[4];
  #pragma unroll
  for (int kb = 0; kb < 4; kb++)
    afr[kb] = *reinterpret_cast<const bf16x8*>(As + (wr + l15) * LDA + kb * 32 + quad * 8);

  f32x4 acc[8] = {};
  #pragma unroll
  for (int ct = 0; ct < 8; ct++) {
    #pragma unroll
    for (int kb = 0; kb < 4; kb++) {
      bf16x8 bfr = *reinterpret_cast<const bf16x8*>(Bs + (ct * 16 + l15) * LDA + kb * 32 + quad * 8);
      acc[ct] = __builtin_amdgcn_mfma_f32_16x16x32_bf16(afr[kb], bfr, acc[ct], 0, 0, 0);
    }
  }

  // epilogue: D row = quad*4+reg, col = ct*16 + l15
  #pragma unroll
  for (int ct = 0; ct < 8; ct++) {
    #pragma unroll
    for (int reg = 0; reg < 4; reg++) {
      int rr = row0 + wr + quad * 4 + reg;
      if (rr >= M) continue;
      int cc = ct * 16 + l15;
      float v = acc[ct][reg];
      if (MODE == 0)
        ((ushort_t*)Cout)[((size_t)blockIdx.y * M + rr) * 128 + cc] = fToBf(v);
      else
        ((float*)Cout)[(size_t)rr * 128 + cc] = v + bias[cc];
    }
  }
}

// -------------------- fused softmax + weighted aggregation -----------------
// One wave per target node. Online (flash-style) softmax over incoming edges;
// lanes cover H=128 as bf16x2 pairs during accumulation. Epilogue: +bias, relu.

__global__ void k_aggr(const ushort_t* __restrict__ feat,   // [R*N][128] bf16
                       const float* __restrict__ si, const float* __restrict__ sj,
                       const int* __restrict__ rowptr, const int* __restrict__ sorted,
                       const float* __restrict__ bias, ushort_t* __restrict__ out,
                       int n) {
  int tid = threadIdx.x, wv = tid >> 6, lane = tid & 63;
  int t = blockIdx.x * 4 + wv;
  if (t >= n) return;
  int e0 = rowptr[t], e1 = rowptr[t + 1];

  float m = -INFINITY, den = 0.f, acc0 = 0.f, acc1 = 0.f;

  for (int base = e0; base < e1; base += 64) {
    int cnt = min(64, e1 - base);
    float alpha = -INFINITY;
    int pk = 0;
    if (lane < cnt) {
      pk = sorted[base + lane];
      int s = pk & 0xFFFF, r = pk >> 16;
      float a = si[t * 8 + r] + sj[s * 8 + r];
      alpha = (a >= 0.f) ? a : 0.2f * a;   // leaky_relu, slope 0.2
    }
    float cm = alpha;
    #pragma unroll
    for (int off = 32; off; off >>= 1) cm = fmaxf(cm, __shfl_xor(cm, off, 64));
    float nm = fmaxf(m, cm);               // finite: cnt >= 1
    float sc = __expf(m - nm);             // first chunk: exp(-inf) = 0
    acc0 *= sc; acc1 *= sc; den *= sc;
    float w = (lane < cnt) ? __expf(alpha - nm) : 0.f;
    float ws = w;
    #pragma unroll
    for (int off = 32; off; off >>= 1) ws += __shfl_xor(ws, off, 64);
    den += ws;
    m = nm;
    // accumulate: broadcast (w, pk) from lane j; lanes cover h = 2*lane, 2*lane+1
    for (int j = 0; j < cnt; j++) {
      float wj = __shfl(w, j, 64);
      int p = __shfl(pk, j, 64);
      int s = p & 0xFFFF, r = p >> 16;
      const ushort_t* row = feat + ((size_t)(r * n + s)) * 128;
      uint v = *(const uint*)(row + lane * 2);
      acc0 += wj * bfToF((ushort_t)(v & 0xFFFF));
      acc1 += wj * bfToF((ushort_t)(v >> 16));
    }
  }
  float inv = (den > 0.f) ? 1.f / (den + 1e-16f) : 0.f;
  acc0 *= inv; acc1 *= inv;
  float o0 = fmaxf(acc0 + bias[lane * 2], 0.f);
  float o1 = fmaxf(acc1 + bias[lane * 2 + 1], 0.f);
  uint po = (uint)fToBf(o0) | ((uint)fToBf(o1) << 16);
  *(uint*)(out + (size_t)t * 128 + lane * 2) = po;
}

// ------------------------------- launcher ----------------------------------

extern "C" void kernel_launch(void* const* d_in, const int* in_sizes, int n_in,
                              void* d_out, int out_size, void* d_ws, size_t ws_size,
                              hipStream_t stream) {
  const float* x   = (const float*)d_in[0];
  const int* ei    = (const int*)d_in[1];
  const int* etype = (const int*)d_in[2];
  const float* W1  = (const float*)d_in[4];
  const float* q1  = (const float*)d_in[5];
  const float* k1  = (const float*)d_in[6];
  const float* b1  = (const float*)d_in[7];
  const float* W2  = (const float*)d_in[8];
  const float* q2  = (const float*)d_in[9];
  const float* k2  = (const float*)d_in[10];
  const float* b2  = (const float*)d_in[11];
  const float* Wl  = (const float*)d_in[12];
  const float* bl  = (const float*)d_in[13];
  float* out       = (float*)d_out;

  const int N = in_sizes[0] / 128;   // 50000
  const int E = in_sizes[2];         // 800000

  char* ws = (char*)d_ws;
  size_t off = 0;
  auto alloc = [&](size_t bytes) {
    size_t o = off;
    off = (off + bytes + 255) & ~(size_t)255;
    return o;
  };

  ushort_t* xbf   = (ushort_t*)(ws + alloc((size_t)N * 128 * 2));
  ushort_t* xW    = (ushort_t*)(ws + alloc((size_t)8 * N * 128 * 2));
  ushort_t* h1    = (ushort_t*)(ws + alloc((size_t)N * 128 * 2));
  ushort_t* h2    = (ushort_t*)(ws + alloc((size_t)N * 128 * 2));
  ushort_t* w1t   = (ushort_t*)(ws + alloc(8 * 128 * 128 * 2));
  ushort_t* w2t   = (ushort_t*)(ws + alloc(8 * 128 * 128 * 2));
  ushort_t* wlt   = (ushort_t*)(ws + alloc(128 * 128 * 2));
  float* si       = (float*)(ws + alloc((size_t)N * 8 * 4));
  float* sj       = (float*)(ws + alloc((size_t)N * 8 * 4));
  float* Wq       = (float*)(ws + alloc(1024 * 4));
  float* Wk       = (float*)(ws + alloc(1024 * 4));
  int* deg        = (int*)(ws + alloc((size_t)N * 4));
  int* cursor     = (int*)(ws + alloc((size_t)N * 4));
  int* incl       = (int*)(ws + alloc((size_t)N * 4));
  int* rowptr     = (int*)(ws + alloc((size_t)(N + 1) * 4));
  int* bsum       = (int*)(ws + alloc(256 * 4));
  int* sorted     = (int*)(ws + alloc((size_t)E * 4));
  (void)ws_size; (void)n_in; (void)out_size;

  const int* srcp = ei;
  const int* tgtp = ei + E;

  int gE  = (E + 255) / 256;          // 3125
  int gN  = (N + 255) / 256;          // 196 (scan blocks)
  int gW  = (N + 3) / 4;              // 12500 (wave-per-node kernels)
  int gM  = (N + 63) / 64;            // 782 (GEMM row tiles)

  // CSR build (once; same graph both layers)
  hipMemsetAsync(deg, 0, (size_t)N * 4, stream);
  hipMemsetAsync(cursor, 0, (size_t)N * 4, stream);
  k_count<<<gE, 256, 0, stream>>>(tgtp, deg, E);
  k_scanA<<<gN, 256, 0, stream>>>(deg, incl, bsum, N);
  k_scanB<<<1, 256, 0, stream>>>(bsum, gN);
  k_scanC<<<gN, 256, 0, stream>>>(deg, incl, bsum, rowptr, N, E);
  k_scatter<<<gE, 256, 0, stream>>>(srcp, tgtp, etype, rowptr, cursor, sorted, E);

  // weight conversions
  k_cvt<<<(N * 128 / 4 + 255) / 256, 256, 0, stream>>>(x, xbf, N * 128 / 4);
  k_wT<<<1024, 128, 0, stream>>>(W1, w1t);
  k_wT<<<1024, 128, 0, stream>>>(W2, w2t);
  k_cvt<<<(128 * 128 / 4 + 255) / 256, 256, 0, stream>>>(Wl, wlt, 128 * 128 / 4);

  // ---- layer 1 ----
  k_wqwk<<<8, 256, 0, stream>>>(W1, q1, k1, Wq, Wk);
  k_sisj<false><<<gW, 256, 0, stream>>>(x, Wq, Wk, si, sj, N);
  k_gemm<0><<<dim3(gM, 8), 256, 0, stream>>>(xbf, w1t, xW, nullptr, N);
  k_aggr<<<gW, 256, 0, stream>>>(xW, si, sj, rowptr, sorted, b1, h1, N);

  // ---- layer 2 ----
  k_wqwk<<<8, 256, 0, stream>>>(W2, q2, k2, Wq, Wk);
  k_sisj<true><<<gW, 256, 0, stream>>>(h1, Wq, Wk, si, sj, N);
  k_gemm<0><<<dim3(gM, 8), 256, 0, stream>>>(h1, w2t, xW, nullptr, N);
  k_aggr<<<gW, 256, 0, stream>>>(xW, si, sj, rowptr, sorted, b2, h2, N);

  // ---- final linear: out = h2 @ Wl^T + bl  (BT layout == Wl row-major) ----
  k_gemm<1><<<dim3(gM, 1), 256, 0, stream>>>(h2, wlt, out, bl, N);
}

// Round 2
// 445.440 us; speedup vs baseline: 1.3328x; 1.3328x over previous
//
#include <hip/hip_runtime.h>

// ---------------------------------------------------------------------------
// RGAT encoder: N=50000, E=800000, R=8, IN=H=128, B=10.
// Per conv layer:
//   k_gemm8: A-tile staged once; loops r=0..7 producing xW[r] (bf16, LDS-repacked
//            coalesced stores) + r=8 "score pass" producing stbl[n][0:8]=x.Wq,
//            [8:16]=x.Wk  (replaces the old k_sisj butterfly kernel).
//   k_aggr : one wave/target, online softmax; accumulation uses 16 lanes/edge,
//            4 edges/group, unroll x4 -> 4 outstanding dwordx4 loads (latency fix).
// Final linear via MFMA GEMM, f32 out + bias. CSR built once.
// ---------------------------------------------------------------------------

typedef unsigned int uint;
typedef unsigned short ushort_t;

using bf16x8 = __attribute__((ext_vector_type(8))) __bf16;
using f32x4  = __attribute__((ext_vector_type(4))) float;

__device__ __forceinline__ ushort_t fToBf(float f) {
  uint u = __float_as_uint(f);
  u += 0x7FFFu + ((u >> 16) & 1);   // round-to-nearest-even
  return (ushort_t)(u >> 16);
}
__device__ __forceinline__ float bfToF(ushort_t h) {
  return __uint_as_float(((uint)h) << 16);
}

// ------------------------------- CSR build ---------------------------------

__global__ void k_count(const int* __restrict__ tgt, int* __restrict__ deg, int E) {
  int e = blockIdx.x * 256 + threadIdx.x;
  if (e < E) atomicAdd(&deg[tgt[e]], 1);
}

__global__ void k_scanA(const int* __restrict__ deg, int* __restrict__ incl,
                        int* __restrict__ bsum, int n) {
  __shared__ int s[256];
  int tid = threadIdx.x;
  int i = blockIdx.x * 256 + tid;
  int v = (i < n) ? deg[i] : 0;
  s[tid] = v;
  __syncthreads();
  for (int off = 1; off < 256; off <<= 1) {
    int t = (tid >= off) ? s[tid - off] : 0;
    __syncthreads();
    s[tid] += t;
    __syncthreads();
  }
  if (i < n) incl[i] = s[tid];
  if (tid == 255) bsum[blockIdx.x] = s[255];
}

__global__ void k_scanB(int* __restrict__ bsum, int nb) {
  __shared__ int s[256];
  int tid = threadIdx.x;
  int v = (tid < nb) ? bsum[tid] : 0;
  s[tid] = v;
  __syncthreads();
  for (int off = 1; off < 256; off <<= 1) {
    int t = (tid >= off) ? s[tid - off] : 0;
    __syncthreads();
    s[tid] += t;
    __syncthreads();
  }
  if (tid < nb) bsum[tid] = s[tid] - v;   // exclusive
}

__global__ void k_scanC(const int* __restrict__ deg, const int* __restrict__ incl,
                        const int* __restrict__ bsum, int* __restrict__ rowptr,
                        int n, int E) {
  int i = blockIdx.x * 256 + threadIdx.x;
  if (i < n) {
    rowptr[i] = bsum[blockIdx.x] + incl[i] - deg[i];  // exclusive scan
    if (i == n - 1) rowptr[n] = E;
  }
}

__global__ void k_scatter(const int* __restrict__ src, const int* __restrict__ tgt,
                          const int* __restrict__ et, const int* __restrict__ rowptr,
                          int* __restrict__ cursor, int* __restrict__ sorted, int E) {
  int e = blockIdx.x * 256 + threadIdx.x;
  if (e >= E) return;
  int t = tgt[e];
  int pos = atomicAdd(&cursor[t], 1);
  sorted[rowptr[t] + pos] = src[e] | (et[e] << 16);   // src < 65536, rel < 8
}

// ------------------------------ conversions --------------------------------

__global__ void k_cvt(const float* __restrict__ in, ushort_t* __restrict__ out, int n4) {
  int i = blockIdx.x * 256 + threadIdx.x;
  if (i >= n4) return;
  float4 v = ((const float4*)in)[i];
  ushort4 o;
  o.x = fToBf(v.x); o.y = fToBf(v.y); o.z = fToBf(v.z); o.w = fToBf(v.w);
  ((ushort4*)out)[i] = o;
}

// WT[r][n][k] = W[r][k][n]  (bf16) — fragment-ready rows for MFMA B operand.
__global__ void k_wT(const float* __restrict__ W, ushort_t* __restrict__ WT) {
  int rn = blockIdx.x;          // r*128 + n
  int r = rn >> 7, n = rn & 127;
  int k = threadIdx.x;          // 128 threads
  WT[(size_t)rn * 128 + k] = fToBf(W[((size_t)r * 128 + k) * 128 + n]);
}

// wqk[16][128] bf16: row r     = Wq[r][kin] = sum_h W[r][kin][h]*q[h]
//                    row 8 + r = Wk[r][kin] = sum_h W[r][kin][h]*k[h]
__global__ void k_wqwk(const float* __restrict__ W, const float* __restrict__ q,
                       const float* __restrict__ k, ushort_t* __restrict__ wqk) {
  int g = blockIdx.x * 256 + threadIdx.x;   // 0..2047
  if (g >= 2048) return;
  int which = g >> 10;
  int idx = g & 1023;                        // r*128 + kin
  const float* w = W + (size_t)idx * 128;
  const float* v = which ? k : q;
  float s = 0.f;
  #pragma unroll 8
  for (int h = 0; h < 128; h++) s += w[h] * v[h];
  int r = idx >> 7, kin = idx & 127;
  wqk[((which << 3) + r) * 128 + kin] = fToBf(s);
}

// ------------------------------- MFMA GEMMs --------------------------------
// Fragment conventions (verified in R1): A-frag m=lane&15 (row), k=quad*8+j;
// B-frag n=lane&15 (col, fragment-ready BT rows); C/D col=lane&15, row=quad*4+reg.

#define LDA 136   // padded LDS stride (bf16 elems)

// One block: 64-row A tile staged once; loop r=0..7 (xW output, LDS-repacked
// bf16 stores) then r=8 (score pass: 16-col output from wqk, f32 direct stores).
__global__ __launch_bounds__(256) void
k_gemm8(const ushort_t* __restrict__ A, const ushort_t* __restrict__ BT8,
        const ushort_t* __restrict__ Wqk, ushort_t* __restrict__ xW,
        float* __restrict__ stbl, int M) {
  __shared__ ushort_t As[64 * LDA];    // A tile; reused as C repack buffer
  __shared__ ushort_t Bs[128 * LDA];
  int tid = threadIdx.x;
  int row0 = blockIdx.x * 64;

  for (int c = tid; c < 1024; c += 256) {
    int r = c >> 4, off = (c & 15) * 8;
    int4 v = {0, 0, 0, 0};
    if (row0 + r < M) v = *(const int4*)(A + (size_t)(row0 + r) * 128 + off);
    *(int4*)(As + r * LDA + off) = v;
  }
  for (int c = tid; c < 2048; c += 256) {
    int nn = c >> 4, off = (c & 15) * 8;
    *(int4*)(Bs + nn * LDA + off) = *(const int4*)(BT8 + (size_t)nn * 128 + off);
  }
  __syncthreads();

  int wv = tid >> 6, lane = tid & 63;
  int l15 = lane & 15, quad = lane >> 4;
  int wr = wv * 16;

  bf16x8 afr[4];   // A fragments live in registers for all 9 passes
  #pragma unroll
  for (int kb = 0; kb < 4; kb++)
    afr[kb] = *reinterpret_cast<const bf16x8*>(As + (wr + l15) * LDA + kb * 32 + quad * 8);

  for (int r = 0; r < 8; r++) {
    f32x4 acc[8] = {};
    #pragma unroll
    for (int ct = 0; ct < 8; ct++) {
      #pragma unroll
      for (int kb = 0; kb < 4; kb++) {
        bf16x8 bfr = *reinterpret_cast<const bf16x8*>(Bs + (ct * 16 + l15) * LDA + kb * 32 + quad * 8);
        acc[ct] = __builtin_amdgcn_mfma_f32_16x16x32_bf16(afr[kb], bfr, acc[ct], 0, 0, 0);
      }
    }
    __syncthreads();   // all waves done reading Bs (and As, first iter)
    // repack C tile (bf16) into As region
    #pragma unroll
    for (int ct = 0; ct < 8; ct++)
      #pragma unroll
      for (int reg = 0; reg < 4; reg++)
        As[(wr + quad * 4 + reg) * LDA + ct * 16 + l15] = fToBf(acc[ct][reg]);
    // stage next B (relation r+1, or the 16-row score table)
    const ushort_t* nb = (r < 7) ? (BT8 + (size_t)(r + 1) * 16384) : Wqk;
    int lim = (r < 7) ? 2048 : 256;
    for (int c = tid; c < lim; c += 256) {
      int nn = c >> 4, off = (c & 15) * 8;
      *(int4*)(Bs + nn * LDA + off) = *(const int4*)(nb + (size_t)nn * 128 + off);
    }
    __syncthreads();   // C tile visible, next B staged
    // coalesced store of C tile
    for (int c = tid; c < 1024; c += 256) {
      int rr = c >> 4, off = (c & 15) * 8;
      if (row0 + rr < M)
        *(int4*)(xW + ((size_t)r * M + row0 + rr) * 128 + off) = *(const int4*)(As + rr * LDA + off);
    }
  }

  // score pass: cols 0..15 = [q-scores | k-scores]
  f32x4 acc = {};
  #pragma unroll
  for (int kb = 0; kb < 4; kb++) {
    bf16x8 bfr = *reinterpret_cast<const bf16x8*>(Bs + l15 * LDA + kb * 32 + quad * 8);
    acc = __builtin_amdgcn_mfma_f32_16x16x32_bf16(afr[kb], bfr, acc, 0, 0, 0);
  }
  #pragma unroll
  for (int reg = 0; reg < 4; reg++) {
    int rr = row0 + wr + quad * 4 + reg;
    if (rr < M) stbl[(size_t)rr * 16 + l15] = acc[reg];
  }
}

// Final linear: out = h2 @ Wl^T + bl, f32 out.
__global__ __launch_bounds__(256) void
k_gemmL(const ushort_t* __restrict__ A, const ushort_t* __restrict__ BT,
        float* __restrict__ Cout, const float* __restrict__ bias, int M) {
  __shared__ ushort_t As[64 * LDA];
  __shared__ ushort_t Bs[128 * LDA];
  int tid = threadIdx.x;
  int row0 = blockIdx.x * 64;
  for (int c = tid; c < 1024; c += 256) {
    int r = c >> 4, off = (c & 15) * 8;
    int4 v = {0, 0, 0, 0};
    if (row0 + r < M) v = *(const int4*)(A + (size_t)(row0 + r) * 128 + off);
    *(int4*)(As + r * LDA + off) = v;
  }
  for (int c = tid; c < 2048; c += 256) {
    int nn = c >> 4, off = (c & 15) * 8;
    *(int4*)(Bs + nn * LDA + off) = *(const int4*)(BT + (size_t)nn * 128 + off);
  }
  __syncthreads();
  int wv = tid >> 6, lane = tid & 63;
  int l15 = lane & 15, quad = lane >> 4;
  int wr = wv * 16;
  bf16x8 afr[4];
  #pragma unroll
  for (int kb = 0; kb < 4; kb++)
    afr[kb] = *reinterpret_cast<const bf16x8*>(As + (wr + l15) * LDA + kb * 32 + quad * 8);
  f32x4 acc[8] = {};
  #pragma unroll
  for (int ct = 0; ct < 8; ct++)
    #pragma unroll
    for (int kb = 0; kb < 4; kb++) {
      bf16x8 bfr = *reinterpret_cast<const bf16x8*>(Bs + (ct * 16 + l15) * LDA + kb * 32 + quad * 8);
      acc[ct] = __builtin_amdgcn_mfma_f32_16x16x32_bf16(afr[kb], bfr, acc[ct], 0, 0, 0);
    }
  #pragma unroll
  for (int ct = 0; ct < 8; ct++)
    #pragma unroll
    for (int reg = 0; reg < 4; reg++) {
      int rr = row0 + wr + quad * 4 + reg;
      if (rr < M) ((float*)Cout)[(size_t)rr * 128 + ct * 16 + l15] = acc[ct][reg] + bias[ct * 16 + l15];
    }
}

// -------------------- fused softmax + weighted aggregation -----------------
// One wave per target. Phase A: per-lane edge weights (online softmax).
// Phase B: 16 lanes/edge (dwordx4 each), 4 edges/group, 4 groups in flight.

#define ACC8(W_, V_)                                                     \
  acc[0] += W_ * bfToF((ushort_t)(V_.x & 0xFFFF));                       \
  acc[1] += W_ * bfToF((ushort_t)(V_.x >> 16));                          \
  acc[2] += W_ * bfToF((ushort_t)(V_.y & 0xFFFF));                       \
  acc[3] += W_ * bfToF((ushort_t)(V_.y >> 16));                          \
  acc[4] += W_ * bfToF((ushort_t)(V_.z & 0xFFFF));                       \
  acc[5] += W_ * bfToF((ushort_t)(V_.z >> 16));                          \
  acc[6] += W_ * bfToF((ushort_t)(V_.w & 0xFFFF));                       \
  acc[7] += W_ * bfToF((ushort_t)(V_.w >> 16));

__global__ __launch_bounds__(256) void
k_aggr(const ushort_t* __restrict__ feat,   // [R*N][128] bf16
       const float* __restrict__ stbl,      // [N][16]: 0..7 q-side, 8..15 k-side
       const int* __restrict__ rowptr, const int* __restrict__ sorted,
       const float* __restrict__ bias, ushort_t* __restrict__ outp, int n) {
  int tid = threadIdx.x, wv = tid >> 6, lane = tid & 63;
  int t = blockIdx.x * 4 + wv;
  if (t >= n) return;
  int e0 = rowptr[t], e1 = rowptr[t + 1];
  int g4 = lane >> 4, fcol = lane & 15;

  float m = -INFINITY, den = 0.f;
  float acc[8] = {};

  for (int base = e0; base < e1; base += 64) {
    int cnt = min(64, e1 - base);
    float alpha = -INFINITY;
    int pk = 0;
    if (lane < cnt) {
      pk = sorted[base + lane];
      int s = pk & 0xFFFF, r = pk >> 16;
      float a = stbl[(size_t)t * 16 + r] + stbl[(size_t)s * 16 + 8 + r];
      alpha = (a >= 0.f) ? a : 0.2f * a;   // leaky_relu 0.2
    }
    float cm = alpha;
    #pragma unroll
    for (int off = 32; off; off >>= 1) cm = fmaxf(cm, __shfl_xor(cm, off, 64));
    float nm = fmaxf(m, cm);
    float sc = __expf(m - nm);             // first chunk: exp(-inf)=0
    den *= sc;
    #pragma unroll
    for (int i = 0; i < 8; i++) acc[i] *= sc;
    float w = (lane < cnt) ? __expf(alpha - nm) : 0.f;
    float ws = w;
    #pragma unroll
    for (int off = 32; off; off >>= 1) ws += __shfl_xor(ws, off, 64);
    den += ws;
    m = nm;

    for (int g = 0; g < cnt; g += 16) {    // 16 edges per iter, 4 loads in flight
      int i0 = g + g4;
      float w0 = __shfl(w, i0, 64);
      float w1 = __shfl(w, i0 + 4, 64);
      float w2 = __shfl(w, i0 + 8, 64);
      float w3 = __shfl(w, i0 + 12, 64);
      int p0 = __shfl(pk, i0, 64);
      int p1 = __shfl(pk, i0 + 4, 64);
      int p2 = __shfl(pk, i0 + 8, 64);
      int p3 = __shfl(pk, i0 + 12, 64);
      const uint4* r0 = (const uint4*)(feat + (size_t)((p0 >> 16) * n + (p0 & 0xFFFF)) * 128) + fcol;
      const uint4* r1 = (const uint4*)(feat + (size_t)((p1 >> 16) * n + (p1 & 0xFFFF)) * 128) + fcol;
      const uint4* r2 = (const uint4*)(feat + (size_t)((p2 >> 16) * n + (p2 & 0xFFFF)) * 128) + fcol;
      const uint4* r3 = (const uint4*)(feat + (size_t)((p3 >> 16) * n + (p3 & 0xFFFF)) * 128) + fcol;
      uint4 v0 = *r0;
      uint4 v1 = *r1;
      uint4 v2 = *r2;
      uint4 v3 = *r3;
      ACC8(w0, v0)
      ACC8(w1, v1)
      ACC8(w2, v2)
      ACC8(w3, v3)
    }
  }

  // combine the 4 edge-slot groups
  #pragma unroll
  for (int i = 0; i < 8; i++) acc[i] += __shfl_xor(acc[i], 16, 64);
  #pragma unroll
  for (int i = 0; i < 8; i++) acc[i] += __shfl_xor(acc[i], 32, 64);

  float inv = (den > 0.f) ? 1.f / (den + 1e-16f) : 0.f;
  uint4 o;
  uint* op = (uint*)&o;
  #pragma unroll
  for (int j = 0; j < 4; j++) {
    float a0 = fmaxf(acc[2 * j] * inv + bias[fcol * 8 + 2 * j], 0.f);
    float a1 = fmaxf(acc[2 * j + 1] * inv + bias[fcol * 8 + 2 * j + 1], 0.f);
    op[j] = (uint)fToBf(a0) | ((uint)fToBf(a1) << 16);
  }
  if (lane < 16) *(uint4*)(outp + (size_t)t * 128 + fcol * 8) = o;
}

// ------------------------------- launcher ----------------------------------

extern "C" void kernel_launch(void* const* d_in, const int* in_sizes, int n_in,
                              void* d_out, int out_size, void* d_ws, size_t ws_size,
                              hipStream_t stream) {
  const float* x   = (const float*)d_in[0];
  const int* ei    = (const int*)d_in[1];
  const int* etype = (const int*)d_in[2];
  const float* W1  = (const float*)d_in[4];
  const float* q1  = (const float*)d_in[5];
  const float* k1  = (const float*)d_in[6];
  const float* b1  = (const float*)d_in[7];
  const float* W2  = (const float*)d_in[8];
  const float* q2  = (const float*)d_in[9];
  const float* k2  = (const float*)d_in[10];
  const float* b2  = (const float*)d_in[11];
  const float* Wl  = (const float*)d_in[12];
  const float* bl  = (const float*)d_in[13];
  float* out       = (float*)d_out;

  const int N = in_sizes[0] / 128;   // 50000
  const int E = in_sizes[2];         // 800000

  char* ws = (char*)d_ws;
  size_t off = 0;
  auto alloc = [&](size_t bytes) {
    size_t o = off;
    off = (off + bytes + 255) & ~(size_t)255;
    return o;
  };

  ushort_t* xbf   = (ushort_t*)(ws + alloc((size_t)N * 128 * 2));
  ushort_t* xW    = (ushort_t*)(ws + alloc((size_t)8 * N * 128 * 2));
  ushort_t* h1    = (ushort_t*)(ws + alloc((size_t)N * 128 * 2));
  ushort_t* h2    = (ushort_t*)(ws + alloc((size_t)N * 128 * 2));
  ushort_t* w1t   = (ushort_t*)(ws + alloc(8 * 128 * 128 * 2));
  ushort_t* w2t   = (ushort_t*)(ws + alloc(8 * 128 * 128 * 2));
  ushort_t* wlt   = (ushort_t*)(ws + alloc(128 * 128 * 2));
  ushort_t* wqk1  = (ushort_t*)(ws + alloc(16 * 128 * 2));
  ushort_t* wqk2  = (ushort_t*)(ws + alloc(16 * 128 * 2));
  float* stbl     = (float*)(ws + alloc((size_t)N * 16 * 4));
  int* deg        = (int*)(ws + alloc((size_t)N * 4));
  int* cursor     = (int*)(ws + alloc((size_t)N * 4));
  int* incl       = (int*)(ws + alloc((size_t)N * 4));
  int* rowptr     = (int*)(ws + alloc((size_t)(N + 1) * 4));
  int* bsum       = (int*)(ws + alloc(256 * 4));
  int* sorted     = (int*)(ws + alloc((size_t)E * 4));
  (void)ws_size; (void)n_in; (void)out_size;

  const int* srcp = ei;
  const int* tgtp = ei + E;

  int gE = (E + 255) / 256;
  int gN = (N + 255) / 256;
  int gW = (N + 3) / 4;
  int gM = (N + 63) / 64;

  // CSR build (once; same graph both layers)
  hipMemsetAsync(deg, 0, (size_t)N * 4, stream);
  hipMemsetAsync(cursor, 0, (size_t)N * 4, stream);
  k_count<<<gE, 256, 0, stream>>>(tgtp, deg, E);
  k_scanA<<<gN, 256, 0, stream>>>(deg, incl, bsum, N);
  k_scanB<<<1, 256, 0, stream>>>(bsum, gN);
  k_scanC<<<gN, 256, 0, stream>>>(deg, incl, bsum, rowptr, N, E);
  k_scatter<<<gE, 256, 0, stream>>>(srcp, tgtp, etype, rowptr, cursor, sorted, E);

  // weight prep
  k_cvt<<<(N * 128 / 4 + 255) / 256, 256, 0, stream>>>(x, xbf, N * 128 / 4);
  k_wT<<<1024, 128, 0, stream>>>(W1, w1t);
  k_wT<<<1024, 128, 0, stream>>>(W2, w2t);
  k_cvt<<<(128 * 128 / 4 + 255) / 256, 256, 0, stream>>>(Wl, wlt, 128 * 128 / 4);
  k_wqwk<<<8, 256, 0, stream>>>(W1, q1, k1, wqk1);
  k_wqwk<<<8, 256, 0, stream>>>(W2, q2, k2, wqk2);

  // layer 1
  k_gemm8<<<gM, 256, 0, stream>>>(xbf, w1t, wqk1, xW, stbl, N);
  k_aggr<<<gW, 256, 0, stream>>>(xW, stbl, rowptr, sorted, b1, h1, N);

  // layer 2
  k_gemm8<<<gM, 256, 0, stream>>>(h1, w2t, wqk2, xW, stbl, N);
  k_aggr<<<gW, 256, 0, stream>>>(xW, stbl, rowptr, sorted, b2, h2, N);

  // final linear
  k_gemmL<<<gM, 256, 0, stream>>>(h2, wlt, out, bl, N);
}

// Round 3
// 439.632 us; speedup vs baseline: 1.3504x; 1.0132x over previous
//
#include <hip/hip_runtime.h>

// ---------------------------------------------------------------------------
// RGAT encoder: N=50000, E=800000, R=8, IN=H=128, B=10.
// k_gemm8 v3 (barrier-free): operandswapped MFMA — A = W^T rows (global/L2),
//   B = x rows (registers, loaded once, reused for 8 relations + score pass).
//   D row = channel -> 4 consecutive channels/lane -> b64 LDS repack (per-wave
//   private, no __syncthreads) -> coalesced dwordx4 stores.
// k_aggr: one wave/target, online softmax, 16 lanes/edge x 4 edges in flight.
// Final linear: classic MFMA GEMM, inline f32->bf16 W conversion.
// ---------------------------------------------------------------------------

typedef unsigned int uint;
typedef unsigned short ushort_t;

using bf16x8 = __attribute__((ext_vector_type(8))) __bf16;
using f32x4  = __attribute__((ext_vector_type(4))) float;

__device__ __forceinline__ ushort_t fToBf(float f) {
  uint u = __float_as_uint(f);
  u += 0x7FFFu + ((u >> 16) & 1);   // round-to-nearest-even
  return (ushort_t)(u >> 16);
}
__device__ __forceinline__ float bfToF(ushort_t h) {
  return __uint_as_float(((uint)h) << 16);
}

// ------------------------------- CSR build ---------------------------------

__global__ void k_count(const int* __restrict__ tgt, int* __restrict__ deg, int E) {
  int e = blockIdx.x * 256 + threadIdx.x;
  if (e < E) atomicAdd(&deg[tgt[e]], 1);
}

__global__ void k_scanA(const int* __restrict__ deg, int* __restrict__ incl,
                        int* __restrict__ bsum, int n) {
  __shared__ int s[256];
  int tid = threadIdx.x;
  int i = blockIdx.x * 256 + tid;
  int v = (i < n) ? deg[i] : 0;
  s[tid] = v;
  __syncthreads();
  for (int off = 1; off < 256; off <<= 1) {
    int t = (tid >= off) ? s[tid - off] : 0;
    __syncthreads();
    s[tid] += t;
    __syncthreads();
  }
  if (i < n) incl[i] = s[tid];
  if (tid == 255) bsum[blockIdx.x] = s[255];
}

__global__ void k_scanB(int* __restrict__ bsum, int nb) {
  __shared__ int s[256];
  int tid = threadIdx.x;
  int v = (tid < nb) ? bsum[tid] : 0;
  s[tid] = v;
  __syncthreads();
  for (int off = 1; off < 256; off <<= 1) {
    int t = (tid >= off) ? s[tid - off] : 0;
    __syncthreads();
    s[tid] += t;
    __syncthreads();
  }
  if (tid < nb) bsum[tid] = s[tid] - v;   // exclusive
}

__global__ void k_scanC(const int* __restrict__ deg, const int* __restrict__ incl,
                        const int* __restrict__ bsum, int* __restrict__ rowptr,
                        int n, int E) {
  int i = blockIdx.x * 256 + threadIdx.x;
  if (i < n) {
    rowptr[i] = bsum[blockIdx.x] + incl[i] - deg[i];
    if (i == n - 1) rowptr[n] = E;
  }
}

__global__ void k_scatter(const int* __restrict__ src, const int* __restrict__ tgt,
                          const int* __restrict__ et, const int* __restrict__ rowptr,
                          int* __restrict__ cursor, int* __restrict__ sorted, int E) {
  int e = blockIdx.x * 256 + threadIdx.x;
  if (e >= E) return;
  int t = tgt[e];
  int pos = atomicAdd(&cursor[t], 1);
  sorted[rowptr[t] + pos] = src[e] | (et[e] << 16);   // src < 65536, rel < 8
}

// ------------------------------ weight prep --------------------------------

// WT[layer][r][n][k] = W_layer[r][k][n]  (bf16). grid 2048 x 128thr.
__global__ void k_wT(const float* __restrict__ W1, const float* __restrict__ W2,
                     ushort_t* __restrict__ WT) {
  int b = blockIdx.x;                 // layer*1024 + r*128 + n
  const float* W = (b >= 1024) ? W2 : W1;
  int rn = b & 1023;
  int r = rn >> 7, n = rn & 127;
  int k = threadIdx.x;
  WT[(size_t)b * 128 + k] = fToBf(W[((size_t)r * 128 + k) * 128 + n]);
}

// wqk[layer][16][128] bf16: rows 0..7 = Wq[r], rows 8..15 = Wk[r].
__global__ void k_wqwk(const float* __restrict__ W1, const float* __restrict__ q1,
                       const float* __restrict__ k1, const float* __restrict__ W2,
                       const float* __restrict__ q2, const float* __restrict__ k2,
                       ushort_t* __restrict__ wqk) {
  int g = blockIdx.x * 256 + threadIdx.x;   // 0..4095
  if (g >= 4096) return;
  int layer = g >> 11;
  int which = (g >> 10) & 1;
  int idx = g & 1023;                        // r*128 + kin
  const float* w = (layer ? W2 : W1) + (size_t)idx * 128;
  const float* v = layer ? (which ? k2 : q2) : (which ? k1 : q1);
  float s = 0.f;
  #pragma unroll 8
  for (int h = 0; h < 128; h++) s += w[h] * v[h];
  int r = idx >> 7, kin = idx & 127;
  wqk[(size_t)layer * 2048 + ((which << 3) + r) * 128 + kin] = fToBf(s);
}

// ------------------------------- MFMA GEMMs --------------------------------
// Fragment conventions (R1/R2-verified): A-frag m=lane&15, k=quad*8+j;
// B-frag n=lane&15, k=quad*8+j; C/D row(m)=quad*4+reg, col(n)=lane&15.

#define LDA 136   // padded LDS stride (bf16 elems)

// Barrier-free 8-relation transform + score pass. Block = 256 thr = 4 waves,
// 128 nodes (32/wave, 2 16-node tiles). A = W^T from global (L2-hot),
// B = x rows in registers. Epilogue via per-wave private LDS repack.
template <bool F32IN>
__global__ __launch_bounds__(256, 3) void
k_gemm8(const void* __restrict__ Ain, const ushort_t* __restrict__ WT,
        const ushort_t* __restrict__ Wqk, ushort_t* __restrict__ xW,
        float* __restrict__ stbl, int M) {
  __shared__ ushort_t rp[4][32 * LDA];
  int tid = threadIdx.x, wv = tid >> 6, lane = tid & 63;
  int l15 = lane & 15, quad = lane >> 4;
  int node0 = blockIdx.x * 128 + wv * 32;
  ushort_t* rpw = rp[wv];

  // load x fragments (registers for all 9 passes)
  bf16x8 bx[2][4];
  #pragma unroll
  for (int nt = 0; nt < 2; nt++) {
    int node = node0 + nt * 16 + l15;
    if (node >= M) node = M - 1;        // clamp; stores are guarded
    if (F32IN) {
      const float* row = (const float*)Ain + (size_t)node * 128;
      #pragma unroll
      for (int kb = 0; kb < 4; kb++) {
        float4 a = *(const float4*)(row + kb * 32 + quad * 8);
        float4 b = *(const float4*)(row + kb * 32 + quad * 8 + 4);
        union { bf16x8 v; ushort_t u[8]; } t;
        t.u[0] = fToBf(a.x); t.u[1] = fToBf(a.y); t.u[2] = fToBf(a.z); t.u[3] = fToBf(a.w);
        t.u[4] = fToBf(b.x); t.u[5] = fToBf(b.y); t.u[6] = fToBf(b.z); t.u[7] = fToBf(b.w);
        bx[nt][kb] = t.v;
      }
    } else {
      const ushort_t* row = (const ushort_t*)Ain + (size_t)node * 128;
      #pragma unroll
      for (int kb = 0; kb < 4; kb++)
        bx[nt][kb] = *(const bf16x8*)(row + kb * 32 + quad * 8);
    }
  }

  for (int r = 0; r < 8; r++) {
    const ushort_t* Wr = WT + (size_t)r * 16384;
    f32x4 acc0[8] = {}, acc1[8] = {};
    #pragma unroll
    for (int mt = 0; mt < 8; mt++) {
      bf16x8 af[4];
      #pragma unroll
      for (int kb = 0; kb < 4; kb++)
        af[kb] = *(const bf16x8*)(Wr + (size_t)(mt * 16 + l15) * 128 + kb * 32 + quad * 8);
      #pragma unroll
      for (int kb = 0; kb < 4; kb++) {
        acc0[mt] = __builtin_amdgcn_mfma_f32_16x16x32_bf16(af[kb], bx[0][kb], acc0[mt], 0, 0, 0);
        acc1[mt] = __builtin_amdgcn_mfma_f32_16x16x32_bf16(af[kb], bx[1][kb], acc1[mt], 0, 0, 0);
      }
    }
    // repack: lane holds channels mt*16+quad*4+[0..3] of node (nt*16+l15)
    #pragma unroll
    for (int mt = 0; mt < 8; mt++) {
      uint2 p0, p1;
      p0.x = (uint)fToBf(acc0[mt][0]) | ((uint)fToBf(acc0[mt][1]) << 16);
      p0.y = (uint)fToBf(acc0[mt][2]) | ((uint)fToBf(acc0[mt][3]) << 16);
      p1.x = (uint)fToBf(acc1[mt][0]) | ((uint)fToBf(acc1[mt][1]) << 16);
      p1.y = (uint)fToBf(acc1[mt][2]) | ((uint)fToBf(acc1[mt][3]) << 16);
      *(uint2*)(rpw + (size_t)l15 * LDA + mt * 16 + quad * 4) = p0;
      *(uint2*)(rpw + (size_t)(16 + l15) * LDA + mt * 16 + quad * 4) = p1;
    }
    // coalesced store (wave-private region; compiler inserts lgkm waits)
    #pragma unroll
    for (int i = 0; i < 8; i++) {
      int row = i * 4 + quad;           // 0..31
      int off = l15 * 8;
      int node = node0 + row;
      if (node < M) {
        int4 v = *(const int4*)(rpw + (size_t)row * LDA + off);
        *(int4*)(xW + ((size_t)r * M + node) * 128 + off) = v;
      }
    }
  }

  // score pass: stbl[node][0..7]=x.Wq[r], [8..15]=x.Wk[r]
  bf16x8 aq[4];
  #pragma unroll
  for (int kb = 0; kb < 4; kb++)
    aq[kb] = *(const bf16x8*)(Wqk + (size_t)l15 * 128 + kb * 32 + quad * 8);
  #pragma unroll
  for (int nt = 0; nt < 2; nt++) {
    f32x4 acc = {};
    #pragma unroll
    for (int kb = 0; kb < 4; kb++)
      acc = __builtin_amdgcn_mfma_f32_16x16x32_bf16(aq[kb], bx[nt][kb], acc, 0, 0, 0);
    int node = node0 + nt * 16 + l15;
    if (node < M) *(float4*)(stbl + (size_t)node * 16 + quad * 4) = *(float4*)&acc;
  }
}

// Final linear: out = h2 @ Wl^T + bl, f32 out. Wl converted inline.
__global__ __launch_bounds__(256) void
k_gemmL(const ushort_t* __restrict__ A, const float* __restrict__ Wl,
        float* __restrict__ Cout, const float* __restrict__ bias, int M) {
  __shared__ ushort_t As[64 * LDA];
  __shared__ ushort_t Bs[128 * LDA];
  int tid = threadIdx.x;
  int row0 = blockIdx.x * 64;
  for (int c = tid; c < 1024; c += 256) {
    int r = c >> 4, off = (c & 15) * 8;
    int4 v = {0, 0, 0, 0};
    if (row0 + r < M) v = *(const int4*)(A + (size_t)(row0 + r) * 128 + off);
    *(int4*)(As + r * LDA + off) = v;
  }
  for (int c = tid; c < 2048; c += 256) {
    int nn = c >> 4, off = (c & 15) * 8;
    float4 a = *(const float4*)(Wl + (size_t)nn * 128 + off);
    float4 b = *(const float4*)(Wl + (size_t)nn * 128 + off + 4);
    ushort_t* d = Bs + nn * LDA + off;
    d[0] = fToBf(a.x); d[1] = fToBf(a.y); d[2] = fToBf(a.z); d[3] = fToBf(a.w);
    d[4] = fToBf(b.x); d[5] = fToBf(b.y); d[6] = fToBf(b.z); d[7] = fToBf(b.w);
  }
  __syncthreads();
  int wv = tid >> 6, lane = tid & 63;
  int l15 = lane & 15, quad = lane >> 4;
  int wr = wv * 16;
  bf16x8 afr[4];
  #pragma unroll
  for (int kb = 0; kb < 4; kb++)
    afr[kb] = *reinterpret_cast<const bf16x8*>(As + (wr + l15) * LDA + kb * 32 + quad * 8);
  f32x4 acc[8] = {};
  #pragma unroll
  for (int ct = 0; ct < 8; ct++)
    #pragma unroll
    for (int kb = 0; kb < 4; kb++) {
      bf16x8 bfr = *reinterpret_cast<const bf16x8*>(Bs + (ct * 16 + l15) * LDA + kb * 32 + quad * 8);
      acc[ct] = __builtin_amdgcn_mfma_f32_16x16x32_bf16(afr[kb], bfr, acc[ct], 0, 0, 0);
    }
  #pragma unroll
  for (int ct = 0; ct < 8; ct++)
    #pragma unroll
    for (int reg = 0; reg < 4; reg++) {
      int rr = row0 + wr + quad * 4 + reg;
      if (rr < M) Cout[(size_t)rr * 128 + ct * 16 + l15] = acc[ct][reg] + bias[ct * 16 + l15];
    }
}

// -------------------- fused softmax + weighted aggregation -----------------

#define ACC8(W_, V_)                                                     \
  acc[0] += W_ * bfToF((ushort_t)(V_.x & 0xFFFF));                       \
  acc[1] += W_ * bfToF((ushort_t)(V_.x >> 16));                          \
  acc[2] += W_ * bfToF((ushort_t)(V_.y & 0xFFFF));                       \
  acc[3] += W_ * bfToF((ushort_t)(V_.y >> 16));                          \
  acc[4] += W_ * bfToF((ushort_t)(V_.z & 0xFFFF));                       \
  acc[5] += W_ * bfToF((ushort_t)(V_.z >> 16));                          \
  acc[6] += W_ * bfToF((ushort_t)(V_.w & 0xFFFF));                       \
  acc[7] += W_ * bfToF((ushort_t)(V_.w >> 16));

__global__ __launch_bounds__(256) void
k_aggr(const ushort_t* __restrict__ feat,   // [R*N][128] bf16
       const float* __restrict__ stbl,      // [N][16]
       const int* __restrict__ rowptr, const int* __restrict__ sorted,
       const float* __restrict__ bias, ushort_t* __restrict__ outp, int n) {
  int tid = threadIdx.x, wv = tid >> 6, lane = tid & 63;
  int t = blockIdx.x * 4 + wv;
  if (t >= n) return;
  int e0 = rowptr[t], e1 = rowptr[t + 1];
  int g4 = lane >> 4, fcol = lane & 15;

  float m = -INFINITY, den = 0.f;
  float acc[8] = {};

  for (int base = e0; base < e1; base += 64) {
    int cnt = min(64, e1 - base);
    float alpha = -INFINITY;
    int pk = 0;
    if (lane < cnt) {
      pk = sorted[base + lane];
      int s = pk & 0xFFFF, r = pk >> 16;
      float a = stbl[(size_t)t * 16 + r] + stbl[(size_t)s * 16 + 8 + r];
      alpha = (a >= 0.f) ? a : 0.2f * a;   // leaky_relu 0.2
    }
    float cm = alpha;
    #pragma unroll
    for (int off = 32; off; off >>= 1) cm = fmaxf(cm, __shfl_xor(cm, off, 64));
    float nm = fmaxf(m, cm);
    float sc = __expf(m - nm);
    den *= sc;
    #pragma unroll
    for (int i = 0; i < 8; i++) acc[i] *= sc;
    float w = (lane < cnt) ? __expf(alpha - nm) : 0.f;
    float ws = w;
    #pragma unroll
    for (int off = 32; off; off >>= 1) ws += __shfl_xor(ws, off, 64);
    den += ws;
    m = nm;

    for (int g = 0; g < cnt; g += 16) {    // 16 edges/iter, 4 dwordx4 in flight
      int i0 = g + g4;
      float w0 = __shfl(w, i0, 64);
      float w1 = __shfl(w, i0 + 4, 64);
      float w2 = __shfl(w, i0 + 8, 64);
      float w3 = __shfl(w, i0 + 12, 64);
      int p0 = __shfl(pk, i0, 64);
      int p1 = __shfl(pk, i0 + 4, 64);
      int p2 = __shfl(pk, i0 + 8, 64);
      int p3 = __shfl(pk, i0 + 12, 64);
      const uint4* r0 = (const uint4*)(feat + (size_t)((p0 >> 16) * n + (p0 & 0xFFFF)) * 128) + fcol;
      const uint4* r1 = (const uint4*)(feat + (size_t)((p1 >> 16) * n + (p1 & 0xFFFF)) * 128) + fcol;
      const uint4* r2 = (const uint4*)(feat + (size_t)((p2 >> 16) * n + (p2 & 0xFFFF)) * 128) + fcol;
      const uint4* r3 = (const uint4*)(feat + (size_t)((p3 >> 16) * n + (p3 & 0xFFFF)) * 128) + fcol;
      uint4 v0 = *r0;
      uint4 v1 = *r1;
      uint4 v2 = *r2;
      uint4 v3 = *r3;
      ACC8(w0, v0)
      ACC8(w1, v1)
      ACC8(w2, v2)
      ACC8(w3, v3)
    }
  }

  #pragma unroll
  for (int i = 0; i < 8; i++) acc[i] += __shfl_xor(acc[i], 16, 64);
  #pragma unroll
  for (int i = 0; i < 8; i++) acc[i] += __shfl_xor(acc[i], 32, 64);

  float inv = (den > 0.f) ? 1.f / (den + 1e-16f) : 0.f;
  uint4 o;
  uint* op = (uint*)&o;
  #pragma unroll
  for (int j = 0; j < 4; j++) {
    float a0 = fmaxf(acc[2 * j] * inv + bias[fcol * 8 + 2 * j], 0.f);
    float a1 = fmaxf(acc[2 * j + 1] * inv + bias[fcol * 8 + 2 * j + 1], 0.f);
    op[j] = (uint)fToBf(a0) | ((uint)fToBf(a1) << 16);
  }
  if (lane < 16) *(uint4*)(outp + (size_t)t * 128 + fcol * 8) = o;
}

// ------------------------------- launcher ----------------------------------

extern "C" void kernel_launch(void* const* d_in, const int* in_sizes, int n_in,
                              void* d_out, int out_size, void* d_ws, size_t ws_size,
                              hipStream_t stream) {
  const float* x   = (const float*)d_in[0];
  const int* ei    = (const int*)d_in[1];
  const int* etype = (const int*)d_in[2];
  const float* W1  = (const float*)d_in[4];
  const float* q1  = (const float*)d_in[5];
  const float* k1  = (const float*)d_in[6];
  const float* b1  = (const float*)d_in[7];
  const float* W2  = (const float*)d_in[8];
  const float* q2  = (const float*)d_in[9];
  const float* k2  = (const float*)d_in[10];
  const float* b2  = (const float*)d_in[11];
  const float* Wl  = (const float*)d_in[12];
  const float* bl  = (const float*)d_in[13];
  float* out       = (float*)d_out;

  const int N = in_sizes[0] / 128;   // 50000
  const int E = in_sizes[2];         // 800000

  char* ws = (char*)d_ws;
  size_t off = 0;
  auto alloc = [&](size_t bytes) {
    size_t o = off;
    off = (off + bytes + 255) & ~(size_t)255;
    return o;
  };

  ushort_t* xW    = (ushort_t*)(ws + alloc((size_t)8 * N * 128 * 2));
  ushort_t* h1    = (ushort_t*)(ws + alloc((size_t)N * 128 * 2));
  ushort_t* h2    = (ushort_t*)(ws + alloc((size_t)N * 128 * 2));
  ushort_t* wT    = (ushort_t*)(ws + alloc((size_t)2 * 8 * 128 * 128 * 2));
  ushort_t* wqk   = (ushort_t*)(ws + alloc(2 * 16 * 128 * 2));
  float* stbl     = (float*)(ws + alloc((size_t)N * 16 * 4));
  int* deg        = (int*)(ws + alloc((size_t)N * 4));
  int* cursor     = (int*)(ws + alloc((size_t)N * 4));
  int* incl       = (int*)(ws + alloc((size_t)N * 4));
  int* rowptr     = (int*)(ws + alloc((size_t)(N + 1) * 4));
  int* bsum       = (int*)(ws + alloc(256 * 4));
  int* sorted     = (int*)(ws + alloc((size_t)E * 4));
  (void)ws_size; (void)n_in; (void)out_size;

  const int* srcp = ei;
  const int* tgtp = ei + E;

  int gE  = (E + 255) / 256;
  int gN  = (N + 255) / 256;
  int gW  = (N + 3) / 4;
  int gM  = (N + 63) / 64;          // gemmL tiles
  int gM2 = (N + 127) / 128;        // gemm8 tiles

  // CSR build (once; same graph both layers)
  hipMemsetAsync(deg, 0, (size_t)N * 4, stream);
  hipMemsetAsync(cursor, 0, (size_t)N * 4, stream);
  k_count<<<gE, 256, 0, stream>>>(tgtp, deg, E);
  k_scanA<<<gN, 256, 0, stream>>>(deg, incl, bsum, N);
  k_scanB<<<1, 256, 0, stream>>>(bsum, gN);
  k_scanC<<<gN, 256, 0, stream>>>(deg, incl, bsum, rowptr, N, E);
  k_scatter<<<gE, 256, 0, stream>>>(srcp, tgtp, etype, rowptr, cursor, sorted, E);

  // weight prep (both layers fused)
  k_wT<<<2048, 128, 0, stream>>>(W1, W2, wT);
  k_wqwk<<<16, 256, 0, stream>>>(W1, q1, k1, W2, q2, k2, wqk);

  // layer 1 (reads f32 x directly)
  k_gemm8<true><<<gM2, 256, 0, stream>>>(x, wT, wqk, xW, stbl, N);
  k_aggr<<<gW, 256, 0, stream>>>(xW, stbl, rowptr, sorted, b1, h1, N);

  // layer 2
  k_gemm8<false><<<gM2, 256, 0, stream>>>(h1, wT + (size_t)8 * 128 * 128,
                                          wqk + 2048, xW, stbl, N);
  k_aggr<<<gW, 256, 0, stream>>>(xW, stbl, rowptr, sorted, b2, h2, N);

  // final linear
  k_gemmL<<<gM, 256, 0, stream>>>(h2, Wl, out, bl, N);
}